// Round 10
// baseline (179.224 us; speedup 1.0000x reference)
//
#include <hip/hip_runtime.h>

#define N_NODES 200000
#define N_EDGES 3200000
#define F 16
#define NB 782                     // buckets of 256 nodes: bucket = dst >> 8
#define NB_PAD 832
#define EPB 8192                   // edges per block (count & partition)
#define EBLOCKS ((N_EDGES + EPB - 1) / EPB)  // 391
#define ET 1024                    // threads for count/partition
#define CAP 5120                   // per-bucket cap (mean 4092, +16 sd)
#define SORT_T 512
#define SPLIT 100000               // src-half split for phase-separated gather
#define GIN_NODES 64               // nodes per gin block (4 threads/node)
#define GIN_BLOCKS ((N_NODES + GIN_NODES - 1) / GIN_NODES) // 3125

// ---------------- helpers ----------------

typedef int   iv4 __attribute__((ext_vector_type(4)));
typedef float fv4 __attribute__((ext_vector_type(4)));

__device__ __forceinline__ int ntload(const int* p) {
    return __builtin_nontemporal_load(p);
}

__device__ __forceinline__ unsigned bf16pack2(float lo, float hi) {
    unsigned ul = __float_as_uint(lo);
    unsigned uh = __float_as_uint(hi);
    ul = (ul + 0x7fffu + ((ul >> 16) & 1u)) >> 16;   // RNE
    uh = (uh + 0x7fffu + ((uh >> 16) & 1u)) >> 16;
    return ul | (uh << 16);
}
#define BLO(w) __uint_as_float((w) << 16)
#define BHI(w) __uint_as_float((w) & 0xffff0000u)

__device__ __forceinline__ void acc8(uint4 w0, uint4 w1, float acc[16]) {
    acc[0]  += BLO(w0.x); acc[1]  += BHI(w0.x);
    acc[2]  += BLO(w0.y); acc[3]  += BHI(w0.y);
    acc[4]  += BLO(w0.z); acc[5]  += BHI(w0.z);
    acc[6]  += BLO(w0.w); acc[7]  += BHI(w0.w);
    acc[8]  += BLO(w1.x); acc[9]  += BHI(w1.x);
    acc[10] += BLO(w1.y); acc[11] += BHI(w1.y);
    acc[12] += BLO(w1.z); acc[13] += BHI(w1.z);
    acc[14] += BLO(w1.w); acc[15] += BHI(w1.w);
}

// gather [lo,hi) stride-4 starting at lo+sub; ebuf via nontemporal loads
__device__ __forceinline__ void gather_range(
    const unsigned short* __restrict__ xin,
    const int* __restrict__ ebuf,
    int lo, int hi, int sub, float acc[16]) {
    int k = lo + sub;
    for (; k + 12 < hi; k += 16) {
        int s0 = ntload(ebuf + k);
        int s1 = ntload(ebuf + k + 4);
        int s2 = ntload(ebuf + k + 8);
        int s3 = ntload(ebuf + k + 12);
        const uint4* r0 = (const uint4*)(xin + (size_t)s0 * F);
        const uint4* r1 = (const uint4*)(xin + (size_t)s1 * F);
        const uint4* r2 = (const uint4*)(xin + (size_t)s2 * F);
        const uint4* r3 = (const uint4*)(xin + (size_t)s3 * F);
        uint4 a0 = r0[0], a1 = r0[1];
        uint4 b0 = r1[0], b1 = r1[1];
        uint4 c0 = r2[0], c1 = r2[1];
        uint4 d0 = r3[0], d1 = r3[1];
        acc8(a0, a1, acc); acc8(b0, b1, acc);
        acc8(c0, c1, acc); acc8(d0, d1, acc);
    }
    for (; k + 4 < hi; k += 8) {
        int s0 = ntload(ebuf + k);
        int s1 = ntload(ebuf + k + 4);
        const uint4* r0 = (const uint4*)(xin + (size_t)s0 * F);
        const uint4* r1 = (const uint4*)(xin + (size_t)s1 * F);
        uint4 a0 = r0[0], a1 = r0[1];
        uint4 b0 = r1[0], b1 = r1[1];
        acc8(a0, a1, acc); acc8(b0, b1, acc);
    }
    if (k < hi) {
        const uint4* r0 = (const uint4*)(xin + (size_t)ntload(ebuf + k) * F);
        acc8(r0[0], r0[1], acc);
    }
}

// ---------------- fp32 -> bf16 table conversion ----------------

__global__ __launch_bounds__(256) void conv_bf16(const float* __restrict__ x,
                                                 unsigned* __restrict__ xb) {
    int i = blockIdx.x * blockDim.x + threadIdx.x;   // 8 floats per thread
    if (i >= N_NODES * F / 8) return;
    const float4* p = (const float4*)(x + (size_t)i * 8);
    float4 a = p[0], b = p[1];
    uint4 r;
    r.x = bf16pack2(a.x, a.y);
    r.y = bf16pack2(a.z, a.w);
    r.z = bf16pack2(b.x, b.y);
    r.w = bf16pack2(b.z, b.w);
    ((uint4*)xb)[i] = r;
}

// ---------------- per-block bucket counts (atomic-free global) ----------------

__global__ __launch_bounds__(ET) void count_kernel(const int* __restrict__ dst,
                                                   int* __restrict__ cntmat) {
    __shared__ int lh[NB];
    const int t = threadIdx.x;
    for (int i = t; i < NB; i += ET) lh[i] = 0;
    __syncthreads();

    const int base4 = blockIdx.x * (EPB / 4);
    #pragma unroll
    for (int k = 0; k < EPB / 4 / ET; ++k) {
        int i4 = base4 + k * ET + t;
        if (i4 < N_EDGES / 4) {
            int4 d = *(const int4*)(dst + i4 * 4);
            atomicAdd(&lh[d.x >> 8], 1);
            atomicAdd(&lh[d.y >> 8], 1);
            atomicAdd(&lh[d.z >> 8], 1);
            atomicAdd(&lh[d.w >> 8], 1);
        }
    }
    __syncthreads();
    int* row = cntmat + (size_t)blockIdx.x * NB_PAD;
    for (int i = t; i < NB; i += ET) row[i] = lh[i];
}

// ---------------- per-bucket column scan ----------------

__global__ __launch_bounds__(512) void colscan(int* __restrict__ cntmat,
                                               int* __restrict__ bcnt) {
    __shared__ int part[512];
    const int t = threadIdx.x;
    const int b = blockIdx.x;          // bucket
    int v = 0;
    if (t < EBLOCKS) v = cntmat[(size_t)t * NB_PAD + b];
    part[t] = v;
    __syncthreads();
    for (int off = 1; off < 512; off <<= 1) {
        int o = (t >= off) ? part[t - off] : 0;
        __syncthreads();
        part[t] += o;
        __syncthreads();
    }
    if (t < EBLOCKS) cntmat[(size_t)t * NB_PAD + b] = part[t] - v;  // exclusive
    if (t == EBLOCKS - 1) bcnt[b] = part[t];                        // total
}

// ---------------- scan bucket totals (one block) ----------------

__global__ __launch_bounds__(1024) void bucket_scan(const int* __restrict__ bcnt,
                                                    int* __restrict__ bbase) {
    __shared__ int part[1024];
    const int t = threadIdx.x;
    int v = (t < NB) ? bcnt[t] : 0;
    part[t] = v;
    __syncthreads();
    for (int off = 1; off < 1024; off <<= 1) {
        int other = (t >= off) ? part[t - off] : 0;
        __syncthreads();
        part[t] += other;
        __syncthreads();
    }
    if (t < NB) bbase[t] = part[t] - v;
    if (t == 1023) bbase[NB] = part[1023];
}

// ---------------- partition scatter (bases precomputed) ----------------
// record = (src << 8) | (dst & 255)

__global__ __launch_bounds__(ET) void partition2(const int* __restrict__ src,
                                                 const int* __restrict__ dst,
                                                 const int* __restrict__ bbase,
                                                 const int* __restrict__ cntmat,
                                                 int* __restrict__ ebuf) {
    __shared__ int lh[NB];      // local cursor
    __shared__ int sbase[NB];   // this block's absolute base per bucket
    const int t = threadIdx.x;
    const int* row = cntmat + (size_t)blockIdx.x * NB_PAD;
    for (int i = t; i < NB; i += ET) {
        sbase[i] = bbase[i] + row[i];
        lh[i] = 0;
    }
    __syncthreads();

    const int base4 = blockIdx.x * (EPB / 4);
    #pragma unroll
    for (int k = 0; k < EPB / 4 / ET; ++k) {
        int i4 = base4 + k * ET + t;
        if (i4 < N_EDGES / 4) {
            int4 s = *(const int4*)(src + i4 * 4);
            int4 d = *(const int4*)(dst + i4 * 4);
            int b, p;
            b = d.x >> 8; p = atomicAdd(&lh[b], 1); ebuf[sbase[b] + p] = (s.x << 8) | (d.x & 255);
            b = d.y >> 8; p = atomicAdd(&lh[b], 1); ebuf[sbase[b] + p] = (s.y << 8) | (d.y & 255);
            b = d.z >> 8; p = atomicAdd(&lh[b], 1); ebuf[sbase[b] + p] = (s.z << 8) | (d.z & 255);
            b = d.w >> 8; p = atomicAdd(&lh[b], 1); ebuf[sbase[b] + p] = (s.w << 8) | (d.w & 255);
        }
    }
}

// ---------------- per-bucket counting sort (key = node, src-half) ----------------
// After: ebuf[noffs[n]..nmid[n]) = src ids < SPLIT; ebuf[nmid[n]..noffs[n+1]) = rest.

__global__ __launch_bounds__(SORT_T) void sort_csr(const int* __restrict__ bbase,
                                                   int* __restrict__ ebuf,
                                                   int* __restrict__ noffs,
                                                   int* __restrict__ nmid,
                                                   int* __restrict__ scratch) {
    __shared__ int srec[CAP];
    __shared__ int hist[512];
    __shared__ int lofs[512];
    const int t = threadIdx.x;
    const int b = blockIdx.x;
    hist[t] = 0;
    __syncthreads();

    const int beg = bbase[b];
    const int end = bbase[b + 1];
    const int sz = end - beg;

    for (int k = beg + t; k < end; k += SORT_T) {
        int rec = ebuf[k];
        int bin = ((rec & 255) << 1) | ((rec >> 8) >= SPLIT);
        atomicAdd(&hist[bin], 1);
    }
    __syncthreads();
    int v = hist[t];
    lofs[t] = v;
    __syncthreads();
    for (int off = 1; off < 512; off <<= 1) {
        int o = (t >= off) ? lofs[t - off] : 0;
        __syncthreads();
        lofs[t] += o;
        __syncthreads();
    }
    const int myend = lofs[t];
    const int mybeg = myend - v;
    __syncthreads();
    hist[t] = mybeg;
    __syncthreads();

    if (sz <= CAP) {
        for (int k = beg + t; k < end; k += SORT_T) {
            int rec = ebuf[k];
            int bin = ((rec & 255) << 1) | ((rec >> 8) >= SPLIT);
            int p = atomicAdd(&hist[bin], 1);
            srec[p] = rec >> 8;
        }
        __syncthreads();
        for (int k = t; k < sz; k += SORT_T) ebuf[beg + k] = srec[k];
    } else {
        // overflow path (statistically never): bounce via global scratch
        for (int k = beg + t; k < end; k += SORT_T) scratch[k] = ebuf[k];
        __syncthreads();
        for (int k = beg + t; k < end; k += SORT_T) {
            int rec = scratch[k];
            int bin = ((rec & 255) << 1) | ((rec >> 8) >= SPLIT);
            int p = atomicAdd(&hist[bin], 1);
            ebuf[beg + p] = rec >> 8;
        }
    }

    const int n = b * 256 + (t >> 1);
    if (n < N_NODES) {
        if ((t & 1) == 0) noffs[n] = beg + mybeg;
        else              nmid[n]  = beg + mybeg;
    }
    if (b == 0 && t == 0) noffs[N_NODES] = N_EDGES;
}

// ---------------- phase A: gather src < SPLIT, store fp32 partials ----------------
// Working set: xin rows [0, SPLIT) = 3.2 MB bf16 -> fits per-XCD L2.

__global__ __launch_bounds__(256) void gin_phaseA(
    const unsigned short* __restrict__ xin,
    const int* __restrict__ noffs,
    const int* __restrict__ nmid,
    const int* __restrict__ ebuf,
    float* __restrict__ accb) {
    const int t = threadIdx.x;
    const int n = blockIdx.x * GIN_NODES + (t >> 2);
    const int sub = t & 3;
    if (n >= N_NODES) return;

    const int beg = noffs[n];
    const int mid = nmid[n];

    float acc[16];
    #pragma unroll
    for (int q = 0; q < 16; ++q) acc[q] = 0.0f;

    gather_range(xin, ebuf, beg, mid, sub, acc);

    #pragma unroll
    for (int q = 0; q < 16; ++q) {
        acc[q] += __shfl_xor(acc[q], 1);
        acc[q] += __shfl_xor(acc[q], 2);
    }
    if (sub != 0) return;

    fv4* row = (fv4*)(accb + (size_t)n * F);
    #pragma unroll
    for (int q = 0; q < 4; ++q) {
        fv4 v = {acc[q * 4 + 0], acc[q * 4 + 1], acc[q * 4 + 2], acc[q * 4 + 3]};
        __builtin_nontemporal_store(v, row + q);
    }
}

// ---------------- phase B: gather src >= SPLIT, add partials, MLP ----------------

template <bool LAYER2>
__global__ __launch_bounds__(256) void gin_phaseB(
    const unsigned short* __restrict__ xin,
    const int* __restrict__ noffs,
    const int* __restrict__ nmid,
    const int* __restrict__ ebuf,
    const float* __restrict__ accb,
    const float* __restrict__ epsp,
    const float* __restrict__ wa, const float* __restrict__ ba,
    const float* __restrict__ wb, const float* __restrict__ bb,
    void* __restrict__ outp) {
    __shared__ float swa[256], swb[256], sba[16], sbb[16];
    const int t = threadIdx.x;
    swa[t] = wa[t];
    swb[t] = wb[t];
    if (t < 16) { sba[t] = ba[t]; sbb[t] = bb[t]; }
    __syncthreads();

    const int n = blockIdx.x * GIN_NODES + (t >> 2);
    const int sub = t & 3;
    if (n >= N_NODES) return;

    const int mid = nmid[n];
    const int end = noffs[n + 1];

    float acc[16];
    #pragma unroll
    for (int q = 0; q < 16; ++q) acc[q] = 0.0f;

    gather_range(xin, ebuf, mid, end, sub, acc);

    #pragma unroll
    for (int q = 0; q < 16; ++q) {
        acc[q] += __shfl_xor(acc[q], 1);
        acc[q] += __shfl_xor(acc[q], 2);
    }
    if (sub != 0) return;

    // add phase-A partials (nontemporal read of own row)
    const fv4* arow = (const fv4*)(accb + (size_t)n * F);
    #pragma unroll
    for (int q = 0; q < 4; ++q) {
        fv4 v = __builtin_nontemporal_load(arow + q);
        acc[q * 4 + 0] += v.x;
        acc[q * 4 + 1] += v.y;
        acc[q * 4 + 2] += v.z;
        acc[q * 4 + 3] += v.w;
    }

    // self term
    const float eps = 1.0f + *epsp;
    const uint4* xr = (const uint4*)(xin + (size_t)n * F);
    uint4 w0 = xr[0], w1 = xr[1];
    float h[16];
    h[0]  = fmaf(eps, BLO(w0.x), acc[0]);   h[1]  = fmaf(eps, BHI(w0.x), acc[1]);
    h[2]  = fmaf(eps, BLO(w0.y), acc[2]);   h[3]  = fmaf(eps, BHI(w0.y), acc[3]);
    h[4]  = fmaf(eps, BLO(w0.z), acc[4]);   h[5]  = fmaf(eps, BHI(w0.z), acc[5]);
    h[6]  = fmaf(eps, BLO(w0.w), acc[6]);   h[7]  = fmaf(eps, BHI(w0.w), acc[7]);
    h[8]  = fmaf(eps, BLO(w1.x), acc[8]);   h[9]  = fmaf(eps, BHI(w1.x), acc[9]);
    h[10] = fmaf(eps, BLO(w1.y), acc[10]);  h[11] = fmaf(eps, BHI(w1.y), acc[11]);
    h[12] = fmaf(eps, BLO(w1.z), acc[12]);  h[13] = fmaf(eps, BHI(w1.z), acc[13]);
    h[14] = fmaf(eps, BLO(w1.w), acc[14]);  h[15] = fmaf(eps, BHI(w1.w), acc[15]);

    float m[16];
    #pragma unroll
    for (int jj = 0; jj < 16; ++jj) {
        float a = sba[jj];
        #pragma unroll
        for (int i = 0; i < 16; ++i) a = fmaf(h[i], swa[i * 16 + jj], a);
        m[jj] = fmaxf(a, 0.0f);
    }

    float o[16];
    #pragma unroll
    for (int jj = 0; jj < 16; ++jj) {
        float a = sbb[jj];
        #pragma unroll
        for (int i = 0; i < 16; ++i) a = fmaf(m[i], swb[i * 16 + jj], a);
        o[jj] = LAYER2 ? a : fmaxf(a, 0.0f);
    }

    if (LAYER2) {
        float mx = o[0];
        #pragma unroll
        for (int jj = 1; jj < 16; ++jj) mx = fmaxf(mx, o[jj]);
        float s = 0.0f;
        #pragma unroll
        for (int jj = 0; jj < 16; ++jj) s += expf(o[jj] - mx);
        float lse = mx + logf(s);
        float* orow = (float*)outp + (size_t)n * F;
        #pragma unroll
        for (int q = 0; q < 4; ++q) {
            ((float4*)orow)[q] = make_float4(o[q * 4 + 0] - lse, o[q * 4 + 1] - lse,
                                             o[q * 4 + 2] - lse, o[q * 4 + 3] - lse);
        }
    } else {
        unsigned* orow = (unsigned*)outp + (size_t)n * 8;
        uint4 r0, r1;
        r0.x = bf16pack2(o[0],  o[1]);   r0.y = bf16pack2(o[2],  o[3]);
        r0.z = bf16pack2(o[4],  o[5]);   r0.w = bf16pack2(o[6],  o[7]);
        r1.x = bf16pack2(o[8],  o[9]);   r1.y = bf16pack2(o[10], o[11]);
        r1.z = bf16pack2(o[12], o[13]);  r1.w = bf16pack2(o[14], o[15]);
        ((uint4*)orow)[0] = r0;
        ((uint4*)orow)[1] = r1;
    }
}

// ---------------- fallback (atomic scatter) kernels ----------------

__global__ __launch_bounds__(256) void scatter_kernel(
    const float* __restrict__ feat,
    const int* __restrict__ src,
    const int* __restrict__ dst,
    float* __restrict__ agg) {
    int e = blockIdx.x * blockDim.x + threadIdx.x;
    if (e >= N_EDGES) return;
    int s = src[e];
    int d = dst[e];
    const float4* fs = (const float4*)(feat + (size_t)s * F);
    float* ad = agg + (size_t)d * F;
    #pragma unroll
    for (int q = 0; q < 4; ++q) {
        float4 v = fs[q];
        atomicAdd(ad + q * 4 + 0, v.x);
        atomicAdd(ad + q * 4 + 1, v.y);
        atomicAdd(ad + q * 4 + 2, v.z);
        atomicAdd(ad + q * 4 + 3, v.w);
    }
}

template <bool RELU_OUT, bool LOGSOFTMAX>
__global__ __launch_bounds__(256) void mlp_kernel(
    const float* __restrict__ xin,
    const float* __restrict__ agg,
    const float* __restrict__ epsp,
    const float* __restrict__ wa, const float* __restrict__ ba,
    const float* __restrict__ wb, const float* __restrict__ bb,
    float* __restrict__ out) {
    __shared__ float swa[256], swb[256], sba[16], sbb[16];
    int t = threadIdx.x;
    swa[t] = wa[t];
    swb[t] = wb[t];
    if (t < 16) { sba[t] = ba[t]; sbb[t] = bb[t]; }
    __syncthreads();

    int n = blockIdx.x * blockDim.x + t;
    if (n >= N_NODES) return;

    float eps = 1.0f + *epsp;
    const float4* xr = (const float4*)(xin + (size_t)n * F);
    const float4* ar = (const float4*)(agg + (size_t)n * F);
    float h[16];
    #pragma unroll
    for (int q = 0; q < 4; ++q) {
        float4 xv = xr[q];
        float4 av = ar[q];
        h[q * 4 + 0] = fmaf(eps, xv.x, av.x);
        h[q * 4 + 1] = fmaf(eps, xv.y, av.y);
        h[q * 4 + 2] = fmaf(eps, xv.z, av.z);
        h[q * 4 + 3] = fmaf(eps, xv.w, av.w);
    }

    float m[16];
    #pragma unroll
    for (int jj = 0; jj < 16; ++jj) {
        float a = sba[jj];
        #pragma unroll
        for (int i = 0; i < 16; ++i) a = fmaf(h[i], swa[i * 16 + jj], a);
        m[jj] = fmaxf(a, 0.0f);
    }

    float o[16];
    #pragma unroll
    for (int jj = 0; jj < 16; ++jj) {
        float a = sbb[jj];
        #pragma unroll
        for (int i = 0; i < 16; ++i) a = fmaf(m[i], swb[i * 16 + jj], a);
        o[jj] = RELU_OUT ? fmaxf(a, 0.0f) : a;
    }

    if (LOGSOFTMAX) {
        float mx = o[0];
        #pragma unroll
        for (int jj = 1; jj < 16; ++jj) mx = fmaxf(mx, o[jj]);
        float s = 0.0f;
        #pragma unroll
        for (int jj = 0; jj < 16; ++jj) s += expf(o[jj] - mx);
        float lse = mx + logf(s);
        #pragma unroll
        for (int jj = 0; jj < 16; ++jj) o[jj] -= lse;
    }

    float4* orow = (float4*)(out + (size_t)n * F);
    #pragma unroll
    for (int q = 0; q < 4; ++q) {
        orow[q] = make_float4(o[q * 4 + 0], o[q * 4 + 1], o[q * 4 + 2], o[q * 4 + 3]);
    }
}

// ---------------- launch ----------------

extern "C" void kernel_launch(void* const* d_in, const int* in_sizes, int n_in,
                              void* d_out, int out_size, void* d_ws, size_t ws_size,
                              hipStream_t stream) {
    const float* x    = (const float*)d_in[0];
    const int*   ei   = (const int*)d_in[1];
    const float* eps1 = (const float*)d_in[2];
    const float* w1a  = (const float*)d_in[3];
    const float* b1a  = (const float*)d_in[4];
    const float* w1b  = (const float*)d_in[5];
    const float* b1b  = (const float*)d_in[6];
    const float* eps2 = (const float*)d_in[7];
    const float* w2a  = (const float*)d_in[8];
    const float* b2a  = (const float*)d_in[9];
    const float* w2b  = (const float*)d_in[10];
    const float* b2b  = (const float*)d_in[11];

    float* out = (float*)d_out;
    const int* src = ei;
    const int* dst = ei + N_EDGES;

    // ws layout: bcnt | bbase | noffs[N+64] | nmid[N+64] | ebuf[E] | xb | hb | cntmat
    size_t off_bcnt   = 0;
    size_t off_bbase  = off_bcnt + (size_t)NB_PAD * 4;
    size_t off_noffs  = off_bbase + (size_t)NB_PAD * 4;
    size_t off_nmid   = off_noffs + ((size_t)N_NODES + 64) * 4;
    size_t off_ebuf   = off_nmid + ((size_t)N_NODES + 64) * 4;
    size_t off_xb     = off_ebuf + (size_t)N_EDGES * 4;
    size_t off_hb     = off_xb + (size_t)N_NODES * F * 2;
    size_t off_cnt    = off_hb + (size_t)N_NODES * F * 2;
    size_t need       = off_cnt + (size_t)EBLOCKS * NB_PAD * 4;

    if (ws_size >= need) {
        int*            bcnt   = (int*)((char*)d_ws + off_bcnt);
        int*            bbase  = (int*)((char*)d_ws + off_bbase);
        int*            noffs  = (int*)((char*)d_ws + off_noffs);
        int*            nmid   = (int*)((char*)d_ws + off_nmid);
        int*            ebuf   = (int*)((char*)d_ws + off_ebuf);
        unsigned short* xb     = (unsigned short*)((char*)d_ws + off_xb);
        unsigned short* hb     = (unsigned short*)((char*)d_ws + off_hb);
        int*            cntmat = (int*)((char*)d_ws + off_cnt);
        float*          accb   = (float*)d_out;   // 12.8 MB fp32 partial buffer

        // ---- build: atomic-free bucket partition + (node, src-half) counting sort ----
        count_kernel<<<EBLOCKS, ET, 0, stream>>>(dst, cntmat);
        conv_bf16<<<(N_NODES * F / 8 + 255) / 256, 256, 0, stream>>>(x, (unsigned*)xb);
        colscan<<<NB, 512, 0, stream>>>(cntmat, bcnt);
        bucket_scan<<<1, 1024, 0, stream>>>(bcnt, bbase);
        partition2<<<EBLOCKS, ET, 0, stream>>>(src, dst, bbase, cntmat, ebuf);
        sort_csr<<<NB, SORT_T, 0, stream>>>(bbase, ebuf, noffs, nmid, (int*)d_out);

        // ---- Layer 1 (phase-separated halves; partials staged in d_out) ----
        gin_phaseA<<<GIN_BLOCKS, 256, 0, stream>>>(xb, noffs, nmid, ebuf, accb);
        gin_phaseB<false><<<GIN_BLOCKS, 256, 0, stream>>>(
            xb, noffs, nmid, ebuf, accb, eps1, w1a, b1a, w1b, b1b, hb);
        // ---- Layer 2 ----
        gin_phaseA<<<GIN_BLOCKS, 256, 0, stream>>>(hb, noffs, nmid, ebuf, accb);
        gin_phaseB<true><<<GIN_BLOCKS, 256, 0, stream>>>(
            hb, noffs, nmid, ebuf, accb, eps2, w2a, b2a, w2b, b2b, out);
    } else {
        // fallback: atomic scatter path (needs only 12.8 MB)
        float* agg = (float*)d_ws;
        const int edge_blocks = (N_EDGES + 255) / 256;
        const int node_blocks = (N_NODES + 255) / 256;
        const size_t agg_bytes = (size_t)N_NODES * F * sizeof(float);

        hipMemsetAsync(agg, 0, agg_bytes, stream);
        scatter_kernel<<<edge_blocks, 256, 0, stream>>>(x, src, dst, agg);
        mlp_kernel<true, false><<<node_blocks, 256, 0, stream>>>(
            x, agg, eps1, w1a, b1a, w1b, b1b, out);

        hipMemsetAsync(agg, 0, agg_bytes, stream);
        scatter_kernel<<<edge_blocks, 256, 0, stream>>>(out, src, dst, agg);
        mlp_kernel<false, true><<<node_blocks, 256, 0, stream>>>(
            out, agg, eps2, w2a, b2a, w2b, b2b, out);
    }
}

// Round 11
// 145.197 us; speedup vs baseline: 1.2343x; 1.2343x over previous
//
#include <hip/hip_runtime.h>

#define N_NODES 200000
#define N_EDGES 3200000
#define F 16
#define NB 782                     // buckets of 256 nodes: bucket = dst >> 8
#define NB_PAD 832
#define EPB 8192                   // edges per block (count & partition)
#define EBLOCKS ((N_EDGES + EPB - 1) / EPB)  // 391
#define ET 1024                    // threads for count/partition
#define CAP 5120                   // per-bucket cap (mean 4092, +16 sd)
#define GIN_NODES 64               // nodes per gin block (4 threads/node)
#define GIN_BLOCKS ((N_NODES + GIN_NODES - 1) / GIN_NODES) // 3125

// ---------------- helpers ----------------

typedef float fv2 __attribute__((ext_vector_type(2)));

__device__ __forceinline__ unsigned bf16pack2(float lo, float hi) {
    unsigned ul = __float_as_uint(lo);
    unsigned uh = __float_as_uint(hi);
    ul = (ul + 0x7fffu + ((ul >> 16) & 1u)) >> 16;   // RNE
    uh = (uh + 0x7fffu + ((uh >> 16) & 1u)) >> 16;
    return ul | (uh << 16);
}
#define BLO(w) __uint_as_float((w) << 16)
#define BHI(w) __uint_as_float((w) & 0xffff0000u)

__device__ __forceinline__ fv2 up2(unsigned w) {
    fv2 v;
    v.x = BLO(w);
    v.y = BHI(w);
    return v;
}

// accumulate one bf16 row (2x uint4) into 8 packed-f32 pairs (v_pk_add_f32)
__device__ __forceinline__ void acc8(uint4 w0, uint4 w1, fv2 acc[8]) {
    acc[0] += up2(w0.x);
    acc[1] += up2(w0.y);
    acc[2] += up2(w0.z);
    acc[3] += up2(w0.w);
    acc[4] += up2(w1.x);
    acc[5] += up2(w1.y);
    acc[6] += up2(w1.z);
    acc[7] += up2(w1.w);
}

// ---------------- fused: per-block bucket counts + fp32->bf16 conversion ----------------

__global__ __launch_bounds__(ET) void count_conv(const int* __restrict__ dst,
                                                 int* __restrict__ cntmat,
                                                 const float* __restrict__ x,
                                                 unsigned* __restrict__ xb) {
    __shared__ int lh[NB];
    const int t = threadIdx.x;
    for (int i = t; i < NB; i += ET) lh[i] = 0;
    __syncthreads();

    // bf16 conversion slice (independent work, hides behind hist atomics)
    {
        int i = blockIdx.x * ET + t;   // one uint4 (8 floats) per thread
        if (i < N_NODES * F / 8) {
            const float4* p = (const float4*)(x + (size_t)i * 8);
            float4 a = p[0], b = p[1];
            uint4 r;
            r.x = bf16pack2(a.x, a.y);
            r.y = bf16pack2(a.z, a.w);
            r.z = bf16pack2(b.x, b.y);
            r.w = bf16pack2(b.z, b.w);
            ((uint4*)xb)[i] = r;
        }
    }

    const int base4 = blockIdx.x * (EPB / 4);
    #pragma unroll
    for (int k = 0; k < EPB / 4 / ET; ++k) {
        int i4 = base4 + k * ET + t;
        if (i4 < N_EDGES / 4) {
            int4 d = *(const int4*)(dst + i4 * 4);
            atomicAdd(&lh[d.x >> 8], 1);
            atomicAdd(&lh[d.y >> 8], 1);
            atomicAdd(&lh[d.z >> 8], 1);
            atomicAdd(&lh[d.w >> 8], 1);
        }
    }
    __syncthreads();
    int* row = cntmat + (size_t)blockIdx.x * NB_PAD;
    for (int i = t; i < NB; i += ET) row[i] = lh[i];
}

// ---------------- per-bucket column scan ----------------

__global__ __launch_bounds__(512) void colscan(int* __restrict__ cntmat,
                                               int* __restrict__ bcnt) {
    __shared__ int part[512];
    const int t = threadIdx.x;
    const int b = blockIdx.x;          // bucket
    int v = 0;
    if (t < EBLOCKS) v = cntmat[(size_t)t * NB_PAD + b];
    part[t] = v;
    __syncthreads();
    for (int off = 1; off < 512; off <<= 1) {
        int o = (t >= off) ? part[t - off] : 0;
        __syncthreads();
        part[t] += o;
        __syncthreads();
    }
    if (t < EBLOCKS) cntmat[(size_t)t * NB_PAD + b] = part[t] - v;  // exclusive
    if (t == EBLOCKS - 1) bcnt[b] = part[t];                        // total
}

// ---------------- scan bucket totals (one block) ----------------

__global__ __launch_bounds__(1024) void bucket_scan(const int* __restrict__ bcnt,
                                                    int* __restrict__ bbase) {
    __shared__ int part[1024];
    const int t = threadIdx.x;
    int v = (t < NB) ? bcnt[t] : 0;
    part[t] = v;
    __syncthreads();
    for (int off = 1; off < 1024; off <<= 1) {
        int other = (t >= off) ? part[t - off] : 0;
        __syncthreads();
        part[t] += other;
        __syncthreads();
    }
    if (t < NB) bbase[t] = part[t] - v;
    if (t == 1023) bbase[NB] = part[1023];
}

// ---------------- partition scatter (bases precomputed) ----------------
// record = (src << 8) | (dst & 255)

__global__ __launch_bounds__(ET) void partition2(const int* __restrict__ src,
                                                 const int* __restrict__ dst,
                                                 const int* __restrict__ bbase,
                                                 const int* __restrict__ cntmat,
                                                 int* __restrict__ ebuf) {
    __shared__ int lh[NB];      // local cursor
    __shared__ int sbase[NB];   // this block's absolute base per bucket
    const int t = threadIdx.x;
    const int* row = cntmat + (size_t)blockIdx.x * NB_PAD;
    for (int i = t; i < NB; i += ET) {
        sbase[i] = bbase[i] + row[i];
        lh[i] = 0;
    }
    __syncthreads();

    const int base4 = blockIdx.x * (EPB / 4);
    #pragma unroll
    for (int k = 0; k < EPB / 4 / ET; ++k) {
        int i4 = base4 + k * ET + t;
        if (i4 < N_EDGES / 4) {
            int4 s = *(const int4*)(src + i4 * 4);
            int4 d = *(const int4*)(dst + i4 * 4);
            int b, p;
            b = d.x >> 8; p = atomicAdd(&lh[b], 1); ebuf[sbase[b] + p] = (s.x << 8) | (d.x & 255);
            b = d.y >> 8; p = atomicAdd(&lh[b], 1); ebuf[sbase[b] + p] = (s.y << 8) | (d.y & 255);
            b = d.z >> 8; p = atomicAdd(&lh[b], 1); ebuf[sbase[b] + p] = (s.z << 8) | (d.z & 255);
            b = d.w >> 8; p = atomicAdd(&lh[b], 1); ebuf[sbase[b] + p] = (s.w << 8) | (d.w & 255);
        }
    }
}

// ---------------- per-bucket counting sort -> in-place node-sorted ebuf + CSR ----------------
// After: ebuf[noffs[n] .. noffs[n+1]) holds SOURCE ids of node n's edges.

__global__ __launch_bounds__(256) void sort_csr(const int* __restrict__ bbase,
                                                int* __restrict__ ebuf,
                                                int* __restrict__ noffs,
                                                int* __restrict__ scratch) {
    __shared__ int srec[CAP];
    __shared__ int hist[256];
    __shared__ int lofs[256];
    const int t = threadIdx.x;
    const int b = blockIdx.x;
    hist[t] = 0;
    __syncthreads();

    const int beg = bbase[b];
    const int end = bbase[b + 1];
    const int sz = end - beg;
    const int n = b * 256 + t;

    for (int k = beg + t; k < end; k += 256)
        atomicAdd(&hist[ebuf[k] & 255], 1);
    __syncthreads();
    int v = hist[t];
    lofs[t] = v;
    __syncthreads();
    for (int off = 1; off < 256; off <<= 1) {
        int o = (t >= off) ? lofs[t - off] : 0;
        __syncthreads();
        lofs[t] += o;
        __syncthreads();
    }
    const int myend = lofs[t];
    const int mybeg = myend - v;
    __syncthreads();
    hist[t] = mybeg;
    __syncthreads();

    if (sz <= CAP) {
        for (int k = beg + t; k < end; k += 256) {
            int rec = ebuf[k];
            int p = atomicAdd(&hist[rec & 255], 1);
            srec[p] = rec >> 8;
        }
        __syncthreads();
        for (int k = t; k < sz; k += 256) ebuf[beg + k] = srec[k];
    } else {
        // overflow path (statistically never): bounce via global scratch
        for (int k = beg + t; k < end; k += 256) scratch[k] = ebuf[k];
        __syncthreads();
        for (int k = beg + t; k < end; k += 256) {
            int rec = scratch[k];
            int p = atomicAdd(&hist[rec & 255], 1);
            ebuf[beg + p] = rec >> 8;
        }
    }

    if (n < N_NODES) noffs[n] = beg + mybeg;
    if (b == 0 && t == 0) noffs[N_NODES] = N_EDGES;
}

// ---------------- CSR gather + MLP (4 threads/node, batch-4, pk-add) ----------------

template <bool LAYER2>
__global__ __launch_bounds__(256) void gin_gather(
    const unsigned short* __restrict__ xin,   // bf16 table [N][16]
    const int* __restrict__ noffs,
    const int* __restrict__ ebuf,             // node-sorted src ids
    const float* __restrict__ epsp,
    const float* __restrict__ wa, const float* __restrict__ ba,
    const float* __restrict__ wb, const float* __restrict__ bb,
    void* __restrict__ outp) {
    __shared__ float swa[256], swb[256], sba[16], sbb[16];
    const int t = threadIdx.x;
    swa[t] = wa[t];
    swb[t] = wb[t];
    if (t < 16) { sba[t] = ba[t]; sbb[t] = bb[t]; }
    __syncthreads();

    const int n = blockIdx.x * GIN_NODES + (t >> 2);
    const int sub = t & 3;
    if (n >= N_NODES) return;

    const int beg = noffs[n];
    const int end = noffs[n + 1];

    fv2 acc2[8];
    #pragma unroll
    for (int q = 0; q < 8; ++q) acc2[q] = (fv2){0.0f, 0.0f};

    int k = beg + sub;
    // batch of 4 records: 8 uint4 loads in flight
    for (; k + 12 < end; k += 16) {
        int s0 = ebuf[k];
        int s1 = ebuf[k + 4];
        int s2 = ebuf[k + 8];
        int s3 = ebuf[k + 12];
        const uint4* r0 = (const uint4*)(xin + (size_t)s0 * F);
        const uint4* r1 = (const uint4*)(xin + (size_t)s1 * F);
        const uint4* r2 = (const uint4*)(xin + (size_t)s2 * F);
        const uint4* r3 = (const uint4*)(xin + (size_t)s3 * F);
        uint4 a0 = r0[0], a1 = r0[1];
        uint4 b0 = r1[0], b1 = r1[1];
        uint4 c0 = r2[0], c1 = r2[1];
        uint4 d0 = r3[0], d1 = r3[1];
        acc8(a0, a1, acc2);
        acc8(b0, b1, acc2);
        acc8(c0, c1, acc2);
        acc8(d0, d1, acc2);
    }
    for (; k + 4 < end; k += 8) {
        int s0 = ebuf[k];
        int s1 = ebuf[k + 4];
        const uint4* r0 = (const uint4*)(xin + (size_t)s0 * F);
        const uint4* r1 = (const uint4*)(xin + (size_t)s1 * F);
        uint4 a0 = r0[0], a1 = r0[1];
        uint4 b0 = r1[0], b1 = r1[1];
        acc8(a0, a1, acc2);
        acc8(b0, b1, acc2);
    }
    if (k < end) {
        const uint4* r0 = (const uint4*)(xin + (size_t)ebuf[k] * F);
        acc8(r0[0], r0[1], acc2);
    }

    float acc[16];
    #pragma unroll
    for (int q = 0; q < 8; ++q) {
        acc[2 * q]     = acc2[q].x;
        acc[2 * q + 1] = acc2[q].y;
    }

    // quad combine
    #pragma unroll
    for (int q = 0; q < 16; ++q) {
        acc[q] += __shfl_xor(acc[q], 1);
        acc[q] += __shfl_xor(acc[q], 2);
    }
    if (sub != 0) return;

    // self term
    const float eps = 1.0f + *epsp;
    const uint4* xr = (const uint4*)(xin + (size_t)n * F);
    uint4 w0 = xr[0], w1 = xr[1];
    float h[16];
    h[0]  = fmaf(eps, BLO(w0.x), acc[0]);   h[1]  = fmaf(eps, BHI(w0.x), acc[1]);
    h[2]  = fmaf(eps, BLO(w0.y), acc[2]);   h[3]  = fmaf(eps, BHI(w0.y), acc[3]);
    h[4]  = fmaf(eps, BLO(w0.z), acc[4]);   h[5]  = fmaf(eps, BHI(w0.z), acc[5]);
    h[6]  = fmaf(eps, BLO(w0.w), acc[6]);   h[7]  = fmaf(eps, BHI(w0.w), acc[7]);
    h[8]  = fmaf(eps, BLO(w1.x), acc[8]);   h[9]  = fmaf(eps, BHI(w1.x), acc[9]);
    h[10] = fmaf(eps, BLO(w1.y), acc[10]);  h[11] = fmaf(eps, BHI(w1.y), acc[11]);
    h[12] = fmaf(eps, BLO(w1.z), acc[12]);  h[13] = fmaf(eps, BHI(w1.z), acc[13]);
    h[14] = fmaf(eps, BLO(w1.w), acc[14]);  h[15] = fmaf(eps, BHI(w1.w), acc[15]);

    float m[16];
    #pragma unroll
    for (int jj = 0; jj < 16; ++jj) {
        float a = sba[jj];
        #pragma unroll
        for (int i = 0; i < 16; ++i) a = fmaf(h[i], swa[i * 16 + jj], a);
        m[jj] = fmaxf(a, 0.0f);
    }

    float o[16];
    #pragma unroll
    for (int jj = 0; jj < 16; ++jj) {
        float a = sbb[jj];
        #pragma unroll
        for (int i = 0; i < 16; ++i) a = fmaf(m[i], swb[i * 16 + jj], a);
        o[jj] = LAYER2 ? a : fmaxf(a, 0.0f);
    }

    if (LAYER2) {
        float mx = o[0];
        #pragma unroll
        for (int jj = 1; jj < 16; ++jj) mx = fmaxf(mx, o[jj]);
        float s = 0.0f;
        #pragma unroll
        for (int jj = 0; jj < 16; ++jj) s += expf(o[jj] - mx);
        float lse = mx + logf(s);
        float* orow = (float*)outp + (size_t)n * F;
        #pragma unroll
        for (int q = 0; q < 4; ++q) {
            ((float4*)orow)[q] = make_float4(o[q * 4 + 0] - lse, o[q * 4 + 1] - lse,
                                             o[q * 4 + 2] - lse, o[q * 4 + 3] - lse);
        }
    } else {
        unsigned* orow = (unsigned*)outp + (size_t)n * 8;
        uint4 r0, r1;
        r0.x = bf16pack2(o[0],  o[1]);   r0.y = bf16pack2(o[2],  o[3]);
        r0.z = bf16pack2(o[4],  o[5]);   r0.w = bf16pack2(o[6],  o[7]);
        r1.x = bf16pack2(o[8],  o[9]);   r1.y = bf16pack2(o[10], o[11]);
        r1.z = bf16pack2(o[12], o[13]);  r1.w = bf16pack2(o[14], o[15]);
        ((uint4*)orow)[0] = r0;
        ((uint4*)orow)[1] = r1;
    }
}

// ---------------- fallback (atomic scatter) kernels ----------------

__global__ __launch_bounds__(256) void scatter_kernel(
    const float* __restrict__ feat,
    const int* __restrict__ src,
    const int* __restrict__ dst,
    float* __restrict__ agg) {
    int e = blockIdx.x * blockDim.x + threadIdx.x;
    if (e >= N_EDGES) return;
    int s = src[e];
    int d = dst[e];
    const float4* fs = (const float4*)(feat + (size_t)s * F);
    float* ad = agg + (size_t)d * F;
    #pragma unroll
    for (int q = 0; q < 4; ++q) {
        float4 v = fs[q];
        atomicAdd(ad + q * 4 + 0, v.x);
        atomicAdd(ad + q * 4 + 1, v.y);
        atomicAdd(ad + q * 4 + 2, v.z);
        atomicAdd(ad + q * 4 + 3, v.w);
    }
}

template <bool RELU_OUT, bool LOGSOFTMAX>
__global__ __launch_bounds__(256) void mlp_kernel(
    const float* __restrict__ xin,
    const float* __restrict__ agg,
    const float* __restrict__ epsp,
    const float* __restrict__ wa, const float* __restrict__ ba,
    const float* __restrict__ wb, const float* __restrict__ bb,
    float* __restrict__ out) {
    __shared__ float swa[256], swb[256], sba[16], sbb[16];
    int t = threadIdx.x;
    swa[t] = wa[t];
    swb[t] = wb[t];
    if (t < 16) { sba[t] = ba[t]; sbb[t] = bb[t]; }
    __syncthreads();

    int n = blockIdx.x * blockDim.x + t;
    if (n >= N_NODES) return;

    float eps = 1.0f + *epsp;
    const float4* xr = (const float4*)(xin + (size_t)n * F);
    const float4* ar = (const float4*)(agg + (size_t)n * F);
    float h[16];
    #pragma unroll
    for (int q = 0; q < 4; ++q) {
        float4 xv = xr[q];
        float4 av = ar[q];
        h[q * 4 + 0] = fmaf(eps, xv.x, av.x);
        h[q * 4 + 1] = fmaf(eps, xv.y, av.y);
        h[q * 4 + 2] = fmaf(eps, xv.z, av.z);
        h[q * 4 + 3] = fmaf(eps, xv.w, av.w);
    }

    float m[16];
    #pragma unroll
    for (int jj = 0; jj < 16; ++jj) {
        float a = sba[jj];
        #pragma unroll
        for (int i = 0; i < 16; ++i) a = fmaf(h[i], swa[i * 16 + jj], a);
        m[jj] = fmaxf(a, 0.0f);
    }

    float o[16];
    #pragma unroll
    for (int jj = 0; jj < 16; ++jj) {
        float a = sbb[jj];
        #pragma unroll
        for (int i = 0; i < 16; ++i) a = fmaf(m[i], swb[i * 16 + jj], a);
        o[jj] = RELU_OUT ? fmaxf(a, 0.0f) : a;
    }

    if (LOGSOFTMAX) {
        float mx = o[0];
        #pragma unroll
        for (int jj = 1; jj < 16; ++jj) mx = fmaxf(mx, o[jj]);
        float s = 0.0f;
        #pragma unroll
        for (int jj = 0; jj < 16; ++jj) s += expf(o[jj] - mx);
        float lse = mx + logf(s);
        #pragma unroll
        for (int jj = 0; jj < 16; ++jj) o[jj] -= lse;
    }

    float4* orow = (float4*)(out + (size_t)n * F);
    #pragma unroll
    for (int q = 0; q < 4; ++q) {
        orow[q] = make_float4(o[q * 4 + 0], o[q * 4 + 1], o[q * 4 + 2], o[q * 4 + 3]);
    }
}

// ---------------- launch ----------------

extern "C" void kernel_launch(void* const* d_in, const int* in_sizes, int n_in,
                              void* d_out, int out_size, void* d_ws, size_t ws_size,
                              hipStream_t stream) {
    const float* x    = (const float*)d_in[0];
    const int*   ei   = (const int*)d_in[1];
    const float* eps1 = (const float*)d_in[2];
    const float* w1a  = (const float*)d_in[3];
    const float* b1a  = (const float*)d_in[4];
    const float* w1b  = (const float*)d_in[5];
    const float* b1b  = (const float*)d_in[6];
    const float* eps2 = (const float*)d_in[7];
    const float* w2a  = (const float*)d_in[8];
    const float* b2a  = (const float*)d_in[9];
    const float* w2b  = (const float*)d_in[10];
    const float* b2b  = (const float*)d_in[11];

    float* out = (float*)d_out;
    const int* src = ei;
    const int* dst = ei + N_EDGES;

    // ws layout: bcnt | bbase | noffs[N+64] | ebuf[E] | xb | hb | cntmat
    size_t off_bcnt   = 0;
    size_t off_bbase  = off_bcnt + (size_t)NB_PAD * 4;
    size_t off_noffs  = off_bbase + (size_t)NB_PAD * 4;
    size_t off_ebuf   = off_noffs + ((size_t)N_NODES + 64) * 4;
    size_t off_xb     = off_ebuf + (size_t)N_EDGES * 4;
    size_t off_hb     = off_xb + (size_t)N_NODES * F * 2;
    size_t off_cnt    = off_hb + (size_t)N_NODES * F * 2;
    size_t need       = off_cnt + (size_t)EBLOCKS * NB_PAD * 4;

    if (ws_size >= need) {
        int*            bcnt   = (int*)((char*)d_ws + off_bcnt);
        int*            bbase  = (int*)((char*)d_ws + off_bbase);
        int*            noffs  = (int*)((char*)d_ws + off_noffs);
        int*            ebuf   = (int*)((char*)d_ws + off_ebuf);
        unsigned short* xb     = (unsigned short*)((char*)d_ws + off_xb);
        unsigned short* hb     = (unsigned short*)((char*)d_ws + off_hb);
        int*            cntmat = (int*)((char*)d_ws + off_cnt);

        // ---- build: fused count+conv, atomic-free partition, counting sort ----
        count_conv<<<EBLOCKS, ET, 0, stream>>>(dst, cntmat, x, (unsigned*)xb);
        colscan<<<NB, 512, 0, stream>>>(cntmat, bcnt);
        bucket_scan<<<1, 1024, 0, stream>>>(bcnt, bbase);
        partition2<<<EBLOCKS, ET, 0, stream>>>(src, dst, bbase, cntmat, ebuf);
        sort_csr<<<NB, 256, 0, stream>>>(bbase, ebuf, noffs, (int*)d_out);

        // ---- Layer 1: hb = bf16(relu(MLP1((1+eps1)*x + agg))) ----
        gin_gather<false><<<GIN_BLOCKS, 256, 0, stream>>>(
            xb, noffs, ebuf, eps1, w1a, b1a, w1b, b1b, hb);
        // ---- Layer 2: out = log_softmax(MLP2((1+eps2)*h + agg)) ----
        gin_gather<true><<<GIN_BLOCKS, 256, 0, stream>>>(
            hb, noffs, ebuf, eps2, w2a, b2a, w2b, b2b, out);
    } else {
        // fallback: atomic scatter path (needs only 12.8 MB)
        float* agg = (float*)d_ws;
        const int edge_blocks = (N_EDGES + 255) / 256;
        const int node_blocks = (N_NODES + 255) / 256;
        const size_t agg_bytes = (size_t)N_NODES * F * sizeof(float);

        hipMemsetAsync(agg, 0, agg_bytes, stream);
        scatter_kernel<<<edge_blocks, 256, 0, stream>>>(x, src, dst, agg);
        mlp_kernel<true, false><<<node_blocks, 256, 0, stream>>>(
            x, agg, eps1, w1a, b1a, w1b, b1b, out);

        hipMemsetAsync(agg, 0, agg_bytes, stream);
        scatter_kernel<<<edge_blocks, 256, 0, stream>>>(out, src, dst, agg);
        mlp_kernel<false, true><<<node_blocks, 256, 0, stream>>>(
            out, agg, eps2, w2a, b2a, w2b, b2b, out);
    }
}